// Round 14
// baseline (4029.146 us; speedup 1.0000x reference)
//
#include <hip/hip_runtime.h>
#include <hip/hip_bf16.h>
#include <stdint.h>
#include <stddef.h>

#define SEQ   512
#define BATCH 64
#define NIN   1024
#define NHID  1024
#define NG    4096   // 4*NHID

typedef __attribute__((ext_vector_type(8))) short bf16x8;
typedef __attribute__((ext_vector_type(4))) float f32x4;
typedef __attribute__((ext_vector_type(4))) uint32_t u32x4;

static __device__ __forceinline__ ushort f2bf(float f) {
  uint32_t u = __builtin_bit_cast(uint32_t, f);
  uint32_t lsb = (u >> 16) & 1u;
  u += 0x7fffu + lsb;           // round-to-nearest-even
  return (ushort)(u >> 16);
}

static __device__ __forceinline__ f32x4 mfma_bf16(bf16x8 a, bf16x8 b, f32x4 c) {
  return __builtin_amdgcn_mfma_f32_16x16x32_bf16(a, b, c, 0, 0, 0);
}

// ---- exchange primitives: DEVICE scope (sc1) -- proven correct r10-r13 ----
static __device__ __forceinline__ void st_short_dev(ushort* p, uint32_t v) {
  asm volatile("global_store_short %0, %1, off sc1" :: "v"(p), "v"(v) : "memory");
}
static __device__ __forceinline__ void st_dword_dev(uint32_t* p, uint32_t v) {
  asm volatile("global_store_dword %0, %1, off sc1" :: "v"(p), "v"(v) : "memory");
}
static __device__ __forceinline__ void st_x4_dev(ushort* p, u32x4 v) {
  asm volatile("global_store_dwordx4 %0, %1, off sc1" :: "v"(p), "v"(v) : "memory");
}
static __device__ __forceinline__ uint32_t ld_dword_dev(const uint32_t* p) {
  uint32_t v;
  asm volatile("global_load_dword %0, %1, off sc1" : "=v"(v) : "v"(p) : "memory");
  return v;
}
static __device__ __forceinline__ u32x4 ld_x4_dev(const ushort* p) {
  u32x4 v;
  asm volatile("global_load_dwordx4 %0, %1, off sc1" : "=v"(v) : "v"(p) : "memory");
  return v;
}

#define WAITV(n) do { asm volatile("s_waitcnt vmcnt(" #n ")" ::: "memory"); \
                      __builtin_amdgcn_sched_barrier(0); } while (0)

// fast transcendentals
static __device__ __forceinline__ float sigm_f(float x) {
  return __builtin_amdgcn_rcpf(1.f + __expf(-x));
}
static __device__ __forceinline__ float tanh_f(float x) {
  return 1.f - 2.f * __builtin_amdgcn_rcpf(__expf(2.f * x) + 1.f);
}

// ---------------- converts ----------------

__global__ __launch_bounds__(256) void k_convert_x(const float* __restrict__ X,
                                                   ushort* __restrict__ Xb, int n4) {
  int i = blockIdx.x * 256 + threadIdx.x;
  if (i < n4) {
    float4 v = ((const float4*)X)[i];
    ushort4 o;
    o.x = f2bf(v.x); o.y = f2bf(v.y); o.z = f2bf(v.z); o.w = f2bf(v.w);
    ((ushort4*)Xb)[i] = o;
  }
}

// permuted row order: p = cg*64 + g*16 + j  <->  r = g*1024 + cg*16 + j
__global__ __launch_bounds__(256) void k_convert_w(const float* __restrict__ W,
                                                   const float* __restrict__ bvec,
                                                   ushort* __restrict__ Wxb,
                                                   ushort* __restrict__ Whb,
                                                   float* __restrict__ bp) {
  int p = blockIdx.x;
  int cg = p >> 6, g = (p >> 4) & 3, j = p & 15;
  int r = g * 1024 + cg * 16 + j;
  const float* src = W + (size_t)r * 2048;
  for (int k4 = threadIdx.x; k4 < 512; k4 += 256) {
    float4 v = ((const float4*)src)[k4];
    ushort4 o;
    o.x = f2bf(v.x); o.y = f2bf(v.y); o.z = f2bf(v.z); o.w = f2bf(v.w);
    if (k4 < 256) ((ushort4*)(Wxb + (size_t)p * 1024))[k4] = o;
    else          ((ushort4*)(Whb + (size_t)p * 1024))[k4 - 256] = o;
  }
  if (threadIdx.x == 0) bp[p] = bvec[r];
}

// zero h ping-pong, c-state, replicated flags (16384 dwords)
__global__ __launch_bounds__(256) void k_zero(ushort* __restrict__ hb0,
                                              ushort* __restrict__ hb1,
                                              float* __restrict__ cst,
                                              uint32_t* __restrict__ flg2) {
  int i = blockIdx.x * 256 + threadIdx.x;  // 65536 total
  st_short_dev(hb0 + i, 0u);
  st_short_dev(hb1 + i, 0u);
  cst[i] = 0.f;
  if (i < 256 * 64) st_dword_dev(flg2 + i, 0u);
}

// ---------------- fully-fused persistent LSTM ----------------
// 256 blocks = 4 teams x 64 hg; block = 16 batches x 64 gate cols; 512 steps
// in ONE launch. Per step the 4 waves split the FULL K=2048 of [x_t, h_{t-1}]:
//   waves 0,1: x-part, K=1024 split in 2. A from Xb (cached normal loads --
//     read-only), B from Wxb (cached). NO dependency -> issues immediately,
//     hidden under the h-waves' poll. This replaces k_gemm1 + the Ax buffer
//     entirely (the x-GEMM now runs in the recurrence's dead time).
//   waves 2,3: h-part, K=1024 split in 2, r12-champion exchange: per-wave
//     fan-in-32 poll of replicated private flags (sc1), then 16x16B sc1 h
//     read with counted-vmcnt slice/MFMA pipeline from fragment-major Wlds.
// All 4 waves accumulate into red[] (one reduce covers x+h). Bias bp hoisted
// to registers (t-invariant). Publish: packed 16B h stores -> wave-drain ->
// replicated flags (proven r12). out (HBM) stores strictly after flags; the
// next step's poll WAITV(0) drains them before the h-load vmcnt pipeline, so
// HBM store latency never enters the slice waits.
// Overwrite safety: union of per-wave gates + the two per-step syncthreads =
// all-64 gate (ping-pong proof unchanged from r7/r12).

__global__ __launch_bounds__(256) void k_persist(const ushort* __restrict__ Whb,
                                                 const ushort* __restrict__ Wxb,
                                                 const ushort* __restrict__ Xb,
                                                 const float* __restrict__ bp,
                                                 ushort* __restrict__ hb0,
                                                 ushort* __restrict__ hb1,
                                                 float* __restrict__ out,
                                                 uint32_t* __restrict__ flg2,
                                                 float* __restrict__ cst) {
  __shared__ ushort Wlds[8192 * 8];     // 128 KB Wh, fragment-major
  __shared__ float red[4][16][65];      // x+h K-split reduce
  __shared__ ushort h_sh[16][16];       // packed publish tile

  const int bid = blockIdx.x;
  const int team = bid >> 6, hg = bid & 63;
  const int tid = threadIdx.x, w = tid >> 6, l = tid & 63;
  const int fr = l & 15, fq = l >> 4;

  // ---- stage Wh slice fragment-major: f = ((kc*4)+bj)*64 + lane ----
  for (int it = 0; it < 32; ++it) {
    int f = it * 256 + tid;
    int fl = f & 63, bj = (f >> 6) & 3, kc = f >> 8;
    bf16x8 v = *(const bf16x8*)(Whb + (size_t)(hg * 64 + bj * 16 + (fl & 15)) * 1024
                                + kc * 32 + (fl >> 4) * 8);
    *(bf16x8*)&Wlds[(size_t)f * 8] = v;
  }
  __syncthreads();

  const int eb = tid >> 4, ej = tid & 15;  // epilogue: batch-in-team, hcol-in-group
  const int hidx_self = (team * 16 + eb) * 1024 + hg * 16 + ej;
  float creg = cst[hidx_self];
  const int pcol = hg * 64;
  const float bpc0 = bp[pcol + ej],      bpc1 = bp[pcol + 16 + ej];
  const float bpc2 = bp[pcol + 32 + ej], bpc3 = bp[pcol + 48 + ej];

  for (int t = 0; t < SEQ; ++t) {
    const ushort* hb_r = (t & 1) ? hb0 : hb1;   // h_{t-1} in buf[(t-1)&1]
    ushort*       hb_w = (t & 1) ? hb1 : hb0;   // h_t -> buf[t&1]

    f32x4 acc[4] = {};

    if (w < 2) {
      // ---- x-part (no dependency): K-span [w*512, +512), cached loads ----
      const ushort* ax_ = Xb + ((size_t)t * 64 + team * 16 + fr) * 1024 + w * 512 + fq * 8;
      const ushort* bx_ = Wxb + (size_t)(hg * 64 + fr) * 1024 + w * 512 + fq * 8;
#pragma unroll
      for (int ks = 0; ks < 16; ++ks) {
        bf16x8 a_ = *(const bf16x8*)(ax_ + ks * 32);
#pragma unroll
        for (int bj = 0; bj < 4; ++bj) {
          bf16x8 b_ = *(const bf16x8*)(bx_ + (size_t)bj * 16 * 1024 + ks * 32);
          acc[bj] = mfma_bf16(a_, b_, acc[bj]);
        }
      }
    } else {
      // ---- h-part: poll my 32 producers, then sc1 h read + MFMA pipeline ----
      const uint32_t* fl_ = flg2 + bid * 64 + (w - 2) * 32 + (l & 31);
      if (t > 0) {
        int guard = 0;
        while (true) {
          uint32_t v = ld_dword_dev(fl_);
          WAITV(0);   // also drains prior-step out stores before h pipeline
          if (__all((int)(v >= (uint32_t)t))) break;
          if (++guard > (1 << 15)) break;   // bug guard: fail visibly
        }
      }
      const ushort* aBt = hb_r + (size_t)(team * 16 + fr) * 1024
                          + (size_t)(w - 2) * 512 + fq * 8;
      u32x4 hv[16];
#pragma unroll
      for (int ks = 0; ks < 16; ++ks) hv[ks] = ld_x4_dev(aBt + ks * 32);
      const int kc0 = (w - 2) * 16;
#define SLICE(ks) do {                                                        \
      bf16x8 a_ = __builtin_bit_cast(bf16x8, hv[ks]);                         \
      _Pragma("unroll")                                                       \
      for (int bj = 0; bj < 4; ++bj) {                                        \
        bf16x8 b_ = *(const bf16x8*)&Wlds[(size_t)(((kc0 + (ks)) * 4 + bj) * 64 + l) * 8]; \
        acc[bj] = mfma_bf16(a_, b_, acc[bj]);                                 \
      }                                                                       \
    } while (0)
      WAITV(15); SLICE(0);
      WAITV(14); SLICE(1);
      WAITV(13); SLICE(2);
      WAITV(12); SLICE(3);
      WAITV(11); SLICE(4);
      WAITV(10); SLICE(5);
      WAITV(9);  SLICE(6);
      WAITV(8);  SLICE(7);
      WAITV(7);  SLICE(8);
      WAITV(6);  SLICE(9);
      WAITV(5);  SLICE(10);
      WAITV(4);  SLICE(11);
      WAITV(3);  SLICE(12);
      WAITV(2);  SLICE(13);
      WAITV(1);  SLICE(14);
      WAITV(0);  SLICE(15);
#undef SLICE
    }

#pragma unroll
    for (int bj = 0; bj < 4; ++bj)
#pragma unroll
      for (int jr = 0; jr < 4; ++jr)
        red[w][fq * 4 + jr][bj * 16 + fr] = acc[bj][jr];
    __syncthreads();

    // ---- epilogue: one (batch, hcol) per thread; bias from registers ----
    float ai_ = bpc0, af_ = bpc1, ao_ = bpc2, ag_ = bpc3;
#pragma unroll
    for (int ww = 0; ww < 4; ++ww) {
      ai_ += red[ww][eb][ej];
      af_ += red[ww][eb][16 + ej];
      ao_ += red[ww][eb][32 + ej];
      ag_ += red[ww][eb][48 + ej];
    }

    float ig = sigm_f(ai_);
    float fg = sigm_f(af_);
    float og = sigm_f(ao_);
    float gg = tanh_f(ag_);
    creg = creg * fg + ig * gg;
    float h = og * tanh_f(creg);
    h_sh[eb][ej] = f2bf(h);
    __syncthreads();   // pack complete + red[] reuse guard + union-of-gates

    // ---- publish (wave0 only): 32 x 16B h stores -> drain -> 64 flags ----
    if (w == 0) {
      if (l < 32) {
        int prow = l >> 1, phalf = (l & 1) * 8;
        u32x4 pv = *(const u32x4*)&h_sh[prow][phalf];
        st_x4_dev(hb_w + (size_t)(team * 16 + prow) * 1024 + hg * 16 + phalf, pv);
      }
      asm volatile("s_waitcnt vmcnt(0)" ::: "memory");   // h visible at L3
      __builtin_amdgcn_sched_barrier(0);
      st_dword_dev(flg2 + (team * 64 + l) * 64 + hg, (uint32_t)(t + 1));
    }

    // ---- out (HBM) stores strictly after flags ----
    out[(size_t)t * 65536 + hidx_self] = h;
    if (t == SEQ - 1) out[(size_t)SEQ * 65536 + hidx_self] = h;
  }

  cst[hidx_self] = creg;
}

// ---------------- host ----------------

extern "C" void kernel_launch(void* const* d_in, const int* in_sizes, int n_in,
                              void* d_out, int out_size, void* d_ws, size_t ws_size,
                              hipStream_t stream) {
  const float* X    = (const float*)d_in[0];
  const float* W    = (const float*)d_in[1];
  const float* bvec = (const float*)d_in[2];
  float* out = (float*)d_out;
  char* ws = (char*)d_ws;

  size_t off = 0;
  auto alloc = [&](size_t bytes) -> char* {
    char* p = ws + off;
    off += (bytes + 255) & ~(size_t)255;
    return p;
  };
  ushort*   Xb   = (ushort*)alloc((size_t)SEQ * BATCH * NIN * 2);
  ushort*   Wxb  = (ushort*)alloc((size_t)NG * NIN * 2);
  ushort*   Whb  = (ushort*)alloc((size_t)NG * NHID * 2);
  float*    bp   = (float*)alloc((size_t)NG * 4);
  ushort*   hb0  = (ushort*)alloc((size_t)BATCH * NHID * 2);
  ushort*   hb1  = (ushort*)alloc((size_t)BATCH * NHID * 2);
  float*    cst  = (float*)alloc((size_t)BATCH * NHID * 4);
  uint32_t* flg2 = (uint32_t*)alloc(256 * 64 * 4);   // replicated flags
  size_t base_need = off;

  if (ws_size < base_need) return;  // ~84 MB required

  k_convert_x<<<(SEQ * BATCH * NIN / 4 + 255) / 256, 256, 0, stream>>>(X, Xb, SEQ * BATCH * NIN / 4);
  k_convert_w<<<NG, 256, 0, stream>>>(W, bvec, Wxb, Whb, bp);
  k_zero<<<BATCH * NHID / 256, 256, 0, stream>>>(hb0, hb1, cst, flg2);

  k_persist<<<256, 256, 0, stream>>>(Whb, Wxb, Xb, bp, hb0, hb1, out, flg2, cst);
}

// Round 15
// 2237.095 us; speedup vs baseline: 1.8011x; 1.8011x over previous
//
#include <hip/hip_runtime.h>
#include <hip/hip_bf16.h>
#include <stdint.h>
#include <stddef.h>

#define SEQ   512
#define BATCH 64
#define NIN   1024
#define NHID  1024
#define NG    4096   // 4*NHID

typedef __attribute__((ext_vector_type(8))) short bf16x8;
typedef __attribute__((ext_vector_type(4))) float f32x4;
typedef __attribute__((ext_vector_type(4))) uint32_t u32x4;

static __device__ __forceinline__ ushort f2bf(float f) {
  uint32_t u = __builtin_bit_cast(uint32_t, f);
  uint32_t lsb = (u >> 16) & 1u;
  u += 0x7fffu + lsb;           // round-to-nearest-even
  return (ushort)(u >> 16);
}
static __device__ __forceinline__ ushort f2h(float f) {
  _Float16 h = (_Float16)f;
  return __builtin_bit_cast(ushort, h);
}
static __device__ __forceinline__ float h2f(ushort u) {
  return (float)__builtin_bit_cast(_Float16, u);
}

static __device__ __forceinline__ f32x4 mfma_bf16(bf16x8 a, bf16x8 b, f32x4 c) {
  return __builtin_amdgcn_mfma_f32_16x16x32_bf16(a, b, c, 0, 0, 0);
}

static __device__ __forceinline__ void lds_load16(const ushort* g, ushort* l) {
  __builtin_amdgcn_global_load_lds(
      (const __attribute__((address_space(1))) void*)g,
      (__attribute__((address_space(3))) void*)l, 16, 0, 0);
}

// ---- exchange primitives: DEVICE scope (sc1) -- proven correct r10-r13 ----
static __device__ __forceinline__ void st_short_dev(ushort* p, uint32_t v) {
  asm volatile("global_store_short %0, %1, off sc1" :: "v"(p), "v"(v) : "memory");
}
static __device__ __forceinline__ void st_dword_dev(uint32_t* p, uint32_t v) {
  asm volatile("global_store_dword %0, %1, off sc1" :: "v"(p), "v"(v) : "memory");
}
static __device__ __forceinline__ void st_x4_dev(ushort* p, u32x4 v) {
  asm volatile("global_store_dwordx4 %0, %1, off sc1" :: "v"(p), "v"(v) : "memory");
}
static __device__ __forceinline__ uint32_t ld_dword_dev(const uint32_t* p) {
  uint32_t v;
  asm volatile("global_load_dword %0, %1, off sc1" : "=v"(v) : "v"(p) : "memory");
  return v;
}
static __device__ __forceinline__ u32x4 ld_x4_dev(const ushort* p) {
  u32x4 v;
  asm volatile("global_load_dwordx4 %0, %1, off sc1" : "=v"(v) : "v"(p) : "memory");
  return v;
}

#define WAITV(n) do { asm volatile("s_waitcnt vmcnt(" #n ")" ::: "memory"); \
                      __builtin_amdgcn_sched_barrier(0); } while (0)

// fast transcendentals
static __device__ __forceinline__ float sigm_f(float x) {
  return __builtin_amdgcn_rcpf(1.f + __expf(-x));
}
static __device__ __forceinline__ float tanh_f(float x) {
  return 1.f - 2.f * __builtin_amdgcn_rcpf(__expf(2.f * x) + 1.f);
}

// ---------------- converts ----------------

__global__ __launch_bounds__(256) void k_convert_x(const float* __restrict__ X,
                                                   ushort* __restrict__ Xb, int n4) {
  int i = blockIdx.x * 256 + threadIdx.x;
  if (i < n4) {
    float4 v = ((const float4*)X)[i];
    ushort4 o;
    o.x = f2bf(v.x); o.y = f2bf(v.y); o.z = f2bf(v.z); o.w = f2bf(v.w);
    ((ushort4*)Xb)[i] = o;
  }
}

// permuted row order: p = cg*64 + g*16 + j  <->  r = g*1024 + cg*16 + j
__global__ __launch_bounds__(256) void k_convert_w(const float* __restrict__ W,
                                                   const float* __restrict__ bvec,
                                                   ushort* __restrict__ Wxb,
                                                   ushort* __restrict__ Whb,
                                                   float* __restrict__ bp) {
  int p = blockIdx.x;
  int cg = p >> 6, g = (p >> 4) & 3, j = p & 15;
  int r = g * 1024 + cg * 16 + j;
  const float* src = W + (size_t)r * 2048;
  for (int k4 = threadIdx.x; k4 < 512; k4 += 256) {
    float4 v = ((const float4*)src)[k4];
    ushort4 o;
    o.x = f2bf(v.x); o.y = f2bf(v.y); o.z = f2bf(v.z); o.w = f2bf(v.w);
    if (k4 < 256) ((ushort4*)(Wxb + (size_t)p * 1024))[k4] = o;
    else          ((ushort4*)(Whb + (size_t)p * 1024))[k4 - 256] = o;
  }
  if (threadIdx.x == 0) bp[p] = bvec[r];
}

// zero h ping-pong, c-state, replicated flags (16384 dwords)
__global__ __launch_bounds__(256) void k_zero(ushort* __restrict__ hb0,
                                              ushort* __restrict__ hb1,
                                              float* __restrict__ cst,
                                              uint32_t* __restrict__ flg2) {
  int i = blockIdx.x * 256 + threadIdx.x;  // 65536 total
  st_short_dev(hb0 + i, 0u);
  st_short_dev(hb1 + i, 0u);
  cst[i] = 0.f;
  if (i < 256 * 64) st_dword_dev(flg2 + i, 0u);
}

// ---------------- GEMM1 chunk: Axc (f16!) = Xbc @ Wxb^T + bp ----------------

__global__ __launch_bounds__(256) void k_gemm1(const ushort* __restrict__ Xbc,
                                               const ushort* __restrict__ Wxb,
                                               const float* __restrict__ bp,
                                               ushort* __restrict__ Axc) {
  __shared__ ushort As[128 * 32];
  __shared__ ushort Bs[128 * 32];
  const int m0 = blockIdx.x * 128;
  const int n0 = blockIdx.y * 128;
  const int tid = threadIdx.x;
  const int w = tid >> 6, l = tid & 63;
  const int wr = w >> 1, wc = w & 1;
  const int lr = l >> 2;
  const int lc = (l & 3) * 8;
  const int fr = l & 15, fk8 = (l >> 4) * 8, fq = l >> 4;

  f32x4 acc[4][4] = {};

  for (int kb = 0; kb < 1024; kb += 32) {
    lds_load16(Xbc + (size_t)(m0 + w * 16 + lr) * 1024 + kb + lc,       &As[w * 512]);
    lds_load16(Xbc + (size_t)(m0 + (w + 4) * 16 + lr) * 1024 + kb + lc, &As[(w + 4) * 512]);
    lds_load16(Wxb + (size_t)(n0 + w * 16 + lr) * 1024 + kb + lc,       &Bs[w * 512]);
    lds_load16(Wxb + (size_t)(n0 + (w + 4) * 16 + lr) * 1024 + kb + lc, &Bs[(w + 4) * 512]);
    __syncthreads();
    bf16x8 af[4], bfr[4];
#pragma unroll
    for (int i = 0; i < 4; i++) af[i]  = *(const bf16x8*)&As[(wr * 64 + i * 16 + fr) * 32 + fk8];
#pragma unroll
    for (int i = 0; i < 4; i++) bfr[i] = *(const bf16x8*)&Bs[(wc * 64 + i * 16 + fr) * 32 + fk8];
#pragma unroll
    for (int i = 0; i < 4; i++)
#pragma unroll
      for (int jj = 0; jj < 4; jj++)
        acc[i][jj] = mfma_bf16(af[i], bfr[jj], acc[i][jj]);
    __syncthreads();
  }

#pragma unroll
  for (int jj = 0; jj < 4; jj++) {
    int gc = n0 + wc * 64 + jj * 16 + fr;
    float bb = bp[gc];
#pragma unroll
    for (int i = 0; i < 4; i++) {
      int grb = m0 + wr * 64 + i * 16 + fq * 4;
#pragma unroll
      for (int jr = 0; jr < 4; jr++)
        Axc[(size_t)(grb + jr) * NG + gc] = f2h(acc[i][jj][jr] + bb);
    }
  }
}

// ---------------- persistent recurrence chunk ----------------
// r13 champion structure + (a) f16 Ax reads, (b) 8-step batched out-stores
// staged in LDS so the poll's WAITV(0) drains an HBM store-ack only 1-in-8
// steps. Everything else unchanged: 256 blocks = 4 teams x 64 hg; 4 waves
// split K; per-wave fan-in-16 poll of replicated private flags (sc1);
// fragment-major Wlds; packed 16B publish -> wave-drain -> replicated flags.

__global__ __launch_bounds__(256) void k_persist(const ushort* __restrict__ Whb,
                                                 const ushort* __restrict__ Axc,
                                                 ushort* __restrict__ hb0,
                                                 ushort* __restrict__ hb1,
                                                 float* __restrict__ out,
                                                 uint32_t* __restrict__ flg2,
                                                 float* __restrict__ cst,
                                                 int t0, int TC) {
  __shared__ ushort Wlds[8192 * 8];     // 128 KB fragment-major
  __shared__ float red[4][16][65];      // K-split reduce
  __shared__ ushort h_sh[16][16];       // packed publish tile
  __shared__ float houtlds[8][256];     // 8-step out staging (8 KB)

  const int bid = blockIdx.x;
  const int team = bid >> 6, hg = bid & 63;
  const int tid = threadIdx.x, w = tid >> 6, l = tid & 63;
  const int fr = l & 15, fq = l >> 4;

  // ---- stage Wh slice fragment-major: f = ((kc*4)+bj)*64 + lane ----
  for (int it = 0; it < 32; ++it) {
    int f = it * 256 + tid;
    int fl = f & 63, bj = (f >> 6) & 3, kc = f >> 8;
    bf16x8 v = *(const bf16x8*)(Whb + (size_t)(hg * 64 + bj * 16 + (fl & 15)) * 1024
                                + kc * 32 + (fl >> 4) * 8);
    *(bf16x8*)&Wlds[(size_t)f * 8] = v;
  }
  __syncthreads();

  const int eb = tid >> 4, ej = tid & 15;  // epilogue: batch-in-team, hcol-in-group
  const int hidx_self = (team * 16 + eb) * 1024 + hg * 16 + ej;
  float creg = cst[hidx_self];

  const size_t roff = (size_t)(team * 16 + fr) * 1024 + w * 256 + fq * 8;
  // fan-in-16: wave w polls ONLY its 16 producers (hg = w*16 + (l&15))
  const uint32_t* fladdr = flg2 + bid * 64 + w * 16 + (l & 15);

  for (int tt = 0; tt < TC; ++tt) {
    const int t = t0 + tt;
    const ushort* hb_r = (t & 1) ? hb0 : hb1;   // h_{t-1} in buf[(t-1)&1]
    ushort*       hb_w = (t & 1) ? hb1 : hb0;   // h_t -> buf[t&1]

    // ---- Ax prefetch (f16, h-independent; overlaps poll) ----
    const ushort* axp = Axc + ((size_t)tt * 64 + team * 16 + eb) * NG + hg * 64;
    ushort axu0 = axp[ej], axu1 = axp[16 + ej], axu2 = axp[32 + ej], axu3 = axp[48 + ej];

    // ---- per-wave 2-deep pipelined poll of 16 producer flags ----
    if (t > 0) {
      int guard = 0;
      while (true) {
        uint32_t v0 = ld_dword_dev(fladdr);
        uint32_t v1 = ld_dword_dev(fladdr);
        asm volatile("s_waitcnt vmcnt(1)" ::: "memory");
        __builtin_amdgcn_sched_barrier(0);
        bool ok0 = __all((int)(v0 >= (uint32_t)t));
        asm volatile("s_waitcnt vmcnt(0)" ::: "memory");
        __builtin_amdgcn_sched_barrier(0);
        if (ok0) break;
        if (__all((int)(v1 >= (uint32_t)t))) break;
        if (++guard > (1 << 15)) break;   // bug guard: fail visibly, don't hang
      }
    }

    // ---- bulk read h_{t-1} (this wave's K-span) + counted-vmcnt pipeline ----
    const ushort* aBt = hb_r + roff;
    u32x4 hv[8];
    f32x4 acc[4] = {};
#pragma unroll
    for (int ks = 0; ks < 8; ++ks) hv[ks] = ld_x4_dev(aBt + ks * 32);
#define SLICE(ks) do {                                                        \
      bf16x8 a_ = __builtin_bit_cast(bf16x8, hv[ks]);                         \
      _Pragma("unroll")                                                       \
      for (int bj = 0; bj < 4; ++bj) {                                        \
        bf16x8 b_ = *(const bf16x8*)&Wlds[(size_t)(((w * 8 + (ks)) * 4 + bj) * 64 + l) * 8]; \
        acc[bj] = mfma_bf16(a_, b_, acc[bj]);                                 \
      }                                                                       \
    } while (0)
    WAITV(7); SLICE(0);
    WAITV(6); SLICE(1);
    WAITV(5); SLICE(2);
    WAITV(4); SLICE(3);
    WAITV(3); SLICE(4);
    WAITV(2); SLICE(5);
    WAITV(1); SLICE(6);
    WAITV(0); SLICE(7);
#undef SLICE

#pragma unroll
    for (int bj = 0; bj < 4; ++bj)
#pragma unroll
      for (int jr = 0; jr < 4; ++jr)
        red[w][fq * 4 + jr][bj * 16 + fr] = acc[bj][jr];
    __syncthreads();

    // ---- epilogue: one (batch, hcol) per thread ----
    float ai_ = h2f(axu0), af_ = h2f(axu1), ao_ = h2f(axu2), ag_ = h2f(axu3);
#pragma unroll
    for (int ww = 0; ww < 4; ++ww) {
      ai_ += red[ww][eb][ej];
      af_ += red[ww][eb][16 + ej];
      ao_ += red[ww][eb][32 + ej];
      ag_ += red[ww][eb][48 + ej];
    }

    float ig = sigm_f(ai_);
    float fg = sigm_f(af_);
    float og = sigm_f(ao_);
    float gg = tanh_f(ag_);
    creg = creg * fg + ig * gg;
    float h = og * tanh_f(creg);
    h_sh[eb][ej] = f2bf(h);
    houtlds[tt & 7][tid] = h;   // out staging (no HBM store this step)
    __syncthreads();   // pack complete + red[] reuse guard + union-of-gates

    // ---- publish (wave0 only): 32 x 16B h stores -> drain -> 64 flags ----
    if (w == 0) {
      if (l < 32) {
        int prow = l >> 1, phalf = (l & 1) * 8;
        u32x4 pv = *(const u32x4*)&h_sh[prow][phalf];
        st_x4_dev(hb_w + (size_t)(team * 16 + prow) * 1024 + hg * 16 + phalf, pv);
      }
      asm volatile("s_waitcnt vmcnt(0)" ::: "memory");   // h visible at L3
      __builtin_amdgcn_sched_barrier(0);
      // replicate flag into each consumer's private slot (fire-and-forget)
      st_dword_dev(flg2 + (team * 64 + l) * 64 + hg, (uint32_t)(t + 1));
    }

    // ---- flush out (HBM) every 8 steps, strictly after flags ----
    if ((tt & 7) == 7) {
      int tb = t - 7;
#pragma unroll
      for (int s = 0; s < 8; ++s)
        out[(size_t)(tb + s) * 65536 + hidx_self] = houtlds[s][tid];
    }
    if (t == SEQ - 1) out[(size_t)SEQ * 65536 + hidx_self] = h;
  }

  cst[hidx_self] = creg;
}

// ---------------- fallback per-step kernel (ws too small for any Ax chunk) ----------------

__global__ __launch_bounds__(256) void k_step(int t,
                                              const ushort* __restrict__ Xb,
                                              const ushort* __restrict__ Wxb,
                                              const ushort* __restrict__ Whb,
                                              const float* __restrict__ bp,
                                              const ushort* __restrict__ hprev,
                                              ushort* __restrict__ hnext,
                                              float* __restrict__ cst,
                                              float* __restrict__ out) {
  __shared__ float red[4][16][65];
  const int bidx = blockIdx.x;
  const int cg = bidx & 63, mb = bidx >> 6;
  const int b0 = mb * 16, pcol = cg * 64;
  const int tid = threadIdx.x, w = tid >> 6, l = tid & 63;
  const int fr = l & 15, fk8 = (l >> 4) * 8, fq = l >> 4;

  f32x4 acc[4] = {};

  const ushort* aSrc;
  const ushort* bMat;
  int kbase;
  if (w < 2) { aSrc = Xb + (size_t)(t * 64 + b0 + fr) * 1024 + w * 512 + fk8; bMat = Wxb; kbase = w * 512; }
  else       { aSrc = hprev + (size_t)(b0 + fr) * 1024 + (w - 2) * 512 + fk8; bMat = Whb; kbase = (w - 2) * 512; }
  const ushort* bRow = bMat + (size_t)(pcol + fr) * 1024 + kbase + fk8;

#pragma unroll
  for (int ks = 0; ks < 16; ks++) {
    int kk = ks * 32;
    bf16x8 a = *(const bf16x8*)(aSrc + kk);
#pragma unroll
    for (int bj = 0; bj < 4; bj++) {
      bf16x8 bfv = *(const bf16x8*)(bRow + (size_t)bj * 16 * 1024 + kk);
      acc[bj] = mfma_bf16(a, bfv, acc[bj]);
    }
  }

#pragma unroll
  for (int bj = 0; bj < 4; bj++)
#pragma unroll
    for (int jr = 0; jr < 4; jr++)
      red[w][fq * 4 + jr][bj * 16 + fr] = acc[bj][jr];
  __syncthreads();

  const int b = tid >> 4, j = tid & 15;
  float ai_ = 0.f, af_ = 0.f, ao_ = 0.f, ag_ = 0.f;
#pragma unroll
  for (int ww = 0; ww < 4; ww++) {
    ai_ += red[ww][b][j];
    af_ += red[ww][b][16 + j];
    ao_ += red[ww][b][32 + j];
    ag_ += red[ww][b][48 + j];
  }
  ai_ += bp[pcol + j]; af_ += bp[pcol + 16 + j]; ao_ += bp[pcol + 32 + j]; ag_ += bp[pcol + 48 + j];

  float ig = sigm_f(ai_);
  float fg = sigm_f(af_);
  float og = sigm_f(ao_);
  float gg = tanh_f(ag_);
  int hidx = (b0 + b) * 1024 + cg * 16 + j;
  float cn = cst[hidx] * fg + ig * gg;
  cst[hidx] = cn;
  float h = og * tanh_f(cn);
  out[(size_t)t * 65536 + hidx] = h;
  hnext[hidx] = f2bf(h);
  if (t == SEQ - 1) out[(size_t)SEQ * 65536 + hidx] = h;
}

// ---------------- host ----------------

extern "C" void kernel_launch(void* const* d_in, const int* in_sizes, int n_in,
                              void* d_out, int out_size, void* d_ws, size_t ws_size,
                              hipStream_t stream) {
  const float* X    = (const float*)d_in[0];
  const float* W    = (const float*)d_in[1];
  const float* bvec = (const float*)d_in[2];
  float* out = (float*)d_out;
  char* ws = (char*)d_ws;

  size_t off = 0;
  auto alloc = [&](size_t bytes) -> char* {
    char* p = ws + off;
    off += (bytes + 255) & ~(size_t)255;
    return p;
  };
  ushort*   Xb   = (ushort*)alloc((size_t)SEQ * BATCH * NIN * 2);
  ushort*   Wxb  = (ushort*)alloc((size_t)NG * NIN * 2);
  ushort*   Whb  = (ushort*)alloc((size_t)NG * NHID * 2);
  float*    bp   = (float*)alloc((size_t)NG * 4);
  ushort*   hb0  = (ushort*)alloc((size_t)BATCH * NHID * 2);
  ushort*   hb1  = (ushort*)alloc((size_t)BATCH * NHID * 2);
  float*    cst  = (float*)alloc((size_t)BATCH * NHID * 4);
  uint32_t* flg2 = (uint32_t*)alloc(256 * 64 * 4);   // replicated flags
  size_t base_need = off;

  if (ws_size < base_need) return;

  // largest chunk length TC (steps) whose f16 Ax chunk fits the remaining ws
  size_t avail = ws_size - base_need;
  int TC = 0;
  for (int tc = 512; tc >= 16; tc >>= 1) {
    if ((size_t)tc * 64 * NG * 2 <= avail) { TC = tc; break; }
  }
  ushort* Axc = (ushort*)(ws + base_need);  // base_need is 256B-aligned

  k_convert_x<<<(SEQ * BATCH * NIN / 4 + 255) / 256, 256, 0, stream>>>(X, Xb, SEQ * BATCH * NIN / 4);
  k_convert_w<<<NG, 256, 0, stream>>>(W, bvec, Wxb, Whb, bp);
  k_zero<<<BATCH * NHID / 256, 256, 0, stream>>>(hb0, hb1, cst, flg2);

  if (TC > 0) {
    for (int c = 0; c < SEQ / TC; ++c) {
      k_gemm1<<<dim3(TC * 64 / 128, NG / 128), 256, 0, stream>>>(
          Xb + (size_t)c * TC * 64 * 1024, Wxb, bp, Axc);
      k_persist<<<256, 256, 0, stream>>>(Whb, Axc, hb0, hb1, out, flg2, cst, c * TC, TC);
    }
  } else {
    for (int t = 0; t < SEQ; t++) {
      const ushort* hp = (t & 1) ? hb1 : hb0;
      ushort*       hn = (t & 1) ? hb0 : hb1;
      k_step<<<256, 256, 0, stream>>>(t, Xb, Wxb, Whb, bp, hp, hn, cst, out);
    }
  }
}